// Round 1
// baseline (118.565 us; speedup 1.0000x reference)
//
#include <hip/hip_runtime.h>

#define B_ 8
#define S_ 512
#define D_ 768
#define L_ 9
#define LAYER0 4
#define LSTRIDE (8*512*768)   // B*S*D elements between layers
#define SCH 8                 // s-chunks for pooling partials

// ---------------- kernel 1: per-token Gram + alpha + token_emb ----------------
__global__ __launch_bounds__(256) void wk_token(const float* __restrict__ hid,
                                                float* __restrict__ te,
                                                float* __restrict__ var_tok) {
  const int token = blockIdx.x;          // b*S + s
  const int b = token >> 9;
  const int s = token & (S_ - 1);
  const int t = threadIdx.x;
  const int lane = t & 63, wid = t >> 6;

  __shared__ float part[4][45];
  __shared__ float G[9][9];
  __shared__ float s_align[9], s_nov[9];

  // each thread owns d = t, t+256, t+512 for all 9 layers
  const float* base = hid + ((((size_t)LAYER0) * B_ + b) * S_ + s) * D_ + t;
  float f[9][3];
#pragma unroll
  for (int l = 0; l < 9; ++l) {
    const float* p = base + (size_t)l * LSTRIDE;
    f[l][0] = p[0];
    f[l][1] = p[256];
    f[l][2] = p[512];
  }

  // per-thread partial Gram (upper triangle, 45 entries)
  float pg[45];
  {
    int q = 0;
#pragma unroll
    for (int i = 0; i < 9; ++i) {
#pragma unroll
      for (int j = i; j < 9; ++j) {
        pg[q] = f[i][0] * f[j][0] + f[i][1] * f[j][1] + f[i][2] * f[j][2];
        ++q;
      }
    }
  }

  // wave-level tree reduce, then cross-wave via LDS
#pragma unroll
  for (int q = 0; q < 45; ++q) {
    float v = pg[q];
    v += __shfl_xor(v, 32);
    v += __shfl_xor(v, 16);
    v += __shfl_xor(v, 8);
    v += __shfl_xor(v, 4);
    v += __shfl_xor(v, 2);
    v += __shfl_xor(v, 1);
    if (lane == 0) part[wid][q] = v;
  }
  __syncthreads();

  if (t < 81) {
    int i = t / 9, j = t % 9;
    int a = i < j ? i : j, c = i < j ? j : i;
    int q = a * 9 - (a * (a - 1)) / 2 + (c - a);
    G[i][j] = part[0][q] + part[1][q] + part[2][q] + part[3][q];
  }
  __syncthreads();

  // lanes 0..8: per-k align/nov via Cholesky on the (<=4)x(<=4) neighbor Gram
  if (t < 9) {
    const int k = t;
    int nb[4]; int m = 0;
    if (k >= 2) { nb[m++] = k - 2; nb[m++] = k - 1; }
    if (k + 1 < 9) nb[m++] = k + 1;
    if (k + 2 < 9) nb[m++] = k + 2;
    const int n = m + 1;

    float g[4], Lc[4][4], tv[4];
    for (int i = 0; i < m; ++i) g[i] = G[nb[i]][k];

    for (int i = 0; i < m; ++i) {
      for (int j = 0; j <= i; ++j) {
        float sum = G[nb[i]][nb[j]];
        for (int p2 = 0; p2 < j; ++p2) sum -= Lc[i][p2] * Lc[j][p2];
        Lc[i][j] = (i == j) ? sqrtf(sum) : sum / Lc[j][j];
      }
    }
    float s2 = 0.f;
    for (int i = 0; i < m; ++i) {
      float sum = g[i];
      for (int p2 = 0; p2 < i; ++p2) sum -= Lc[i][p2] * tv[p2];
      tv[i] = sum / Lc[i][i];
      s2 += tv[i] * tv[i];
    }
    float ar = 0.f;
    for (int i = 0; i < m; ++i) ar += g[i] / sqrtf(G[nb[i]][nb[i]]);
    ar /= (float)m;

    float align = sqrtf(s2) / (ar * (2.0f * (float)n));
    float Gkk = G[k][k];
    float nov = sqrtf(fmaxf(Gkk - s2, 0.f)) / sqrtf(Gkk);
    s_align[k] = align;
    s_nov[k] = nov;
  }
  // lane 9: token cosine-variance
  if (t == 9) {
    float sc = 0.f, sc2 = 0.f;
    for (int i = 0; i < 8; ++i) {
      float nn = sqrtf(G[i][i]) * sqrtf(G[i + 1][i + 1]);
      nn = fmaxf(nn, 1e-8f);
      float ci = G[i][i + 1] / nn;
      sc += ci; sc2 += ci * ci;
    }
    float mean = sc * 0.125f;
    var_tok[token] = (sc2 - 8.f * mean * mean) * (1.f / 7.f);
  }
  __syncthreads();

  // all threads: normalize alpha, form token embedding for their 3 d's
  float sa = 0.f, sn = 0.f;
#pragma unroll
  for (int l = 0; l < 9; ++l) { sa += s_align[l]; sn += s_nov[l]; }
  float alpha[9]; float ss = 0.f;
#pragma unroll
  for (int l = 0; l < 9; ++l) { alpha[l] = s_align[l] / sa + s_nov[l] / sn; ss += alpha[l]; }
  float inv = 1.f / ss;
  float t0 = 0.f, t1 = 0.f, t2 = 0.f;
#pragma unroll
  for (int l = 0; l < 9; ++l) {
    float a = alpha[l] * inv;
    t0 += a * f[l][0];
    t1 += a * f[l][1];
    t2 += a * f[l][2];
  }
  float* o = te + (size_t)token * D_ + t;
  o[0] = t0; o[256] = t1; o[512] = t2;
}

// ---------------- kernel 2: masked variance weights, normalized per batch ----------------
__global__ __launch_bounds__(512) void wk_vnorm(const int* __restrict__ mask,
                                                const float* __restrict__ var_tok,
                                                float* __restrict__ v) {
  const int b = blockIdx.x, s = threadIdx.x;
  const int lane = s & 63, wid = s >> 6;
  __shared__ int redi[8];
  __shared__ float redf[8];

  int m = mask[b * S_ + s];
  int mm = m;
  mm += __shfl_xor(mm, 32); mm += __shfl_xor(mm, 16); mm += __shfl_xor(mm, 8);
  mm += __shfl_xor(mm, 4);  mm += __shfl_xor(mm, 2);  mm += __shfl_xor(mm, 1);
  if (lane == 0) redi[wid] = mm;
  __syncthreads();
  int tot = 0;
#pragma unroll
  for (int w = 0; w < 8; ++w) tot += redi[w];
  const int len = tot - 1;

  float val = (s < len) ? var_tok[b * S_ + s] : 0.f;
  float vv = val;
  vv += __shfl_xor(vv, 32); vv += __shfl_xor(vv, 16); vv += __shfl_xor(vv, 8);
  vv += __shfl_xor(vv, 4);  vv += __shfl_xor(vv, 2);  vv += __shfl_xor(vv, 1);
  if (lane == 0) redf[wid] = vv;
  __syncthreads();
  float sum = 0.f;
#pragma unroll
  for (int w = 0; w < 8; ++w) sum += redf[w];

  v[b * S_ + s] = val / sum;
}

// ---------------- kernel 3a: partial weighted pooling over s-chunks ----------------
__global__ __launch_bounds__(256) void wk_pool_partial(const float* __restrict__ te,
                                                       const float* __restrict__ v,
                                                       float* __restrict__ P) {
  const int b = blockIdx.x / SCH;
  const int c = blockIdx.x % SCH;
  const int t = threadIdx.x;
  __shared__ float vl[S_ / SCH];
  if (t < S_ / SCH) vl[t] = v[b * S_ + c * (S_ / SCH) + t];
  __syncthreads();

  float a0 = 0.f, a1 = 0.f, a2 = 0.f;
  const float* base = te + ((size_t)b * S_ + c * (S_ / SCH)) * D_;
#pragma unroll 4
  for (int s = 0; s < S_ / SCH; ++s) {
    const float* p = base + (size_t)s * D_;
    float w = vl[s];
    a0 += w * p[t];
    a1 += w * p[t + 256];
    a2 += w * p[t + 512];
  }
  float* Pp = P + (size_t)blockIdx.x * D_;
  Pp[t] = a0; Pp[t + 256] = a1; Pp[t + 512] = a2;
}

// ---------------- kernel 3b: combine partials ----------------
__global__ __launch_bounds__(256) void wk_pool_final(const float* __restrict__ P,
                                                     float* __restrict__ out) {
  const int i = blockIdx.x * 256 + threadIdx.x;   // 0 .. B*D-1
  const int b = i / D_;
  const int d = i % D_;
  float acc = 0.f;
#pragma unroll
  for (int c = 0; c < SCH; ++c) acc += P[((size_t)b * SCH + c) * D_ + d];
  out[i] = acc;
}

extern "C" void kernel_launch(void* const* d_in, const int* in_sizes, int n_in,
                              void* d_out, int out_size, void* d_ws, size_t ws_size,
                              hipStream_t stream) {
  const float* hid = (const float*)d_in[0];       // (13, 8, 512, 768) f32
  const int* mask = (const int*)d_in[1];          // (8, 512) i32
  float* out = (float*)d_out;                     // (8, 768) f32

  float* te      = (float*)d_ws;                  // B*S*D
  float* var_tok = te + (size_t)B_ * S_ * D_;     // B*S
  float* v       = var_tok + B_ * S_;             // B*S
  float* P       = v + B_ * S_;                   // B*SCH*D

  wk_token<<<B_ * S_, 256, 0, stream>>>(hid, te, var_tok);
  wk_vnorm<<<B_, 512, 0, stream>>>(mask, var_tok, v);
  wk_pool_partial<<<B_ * SCH, 256, 0, stream>>>(te, v, P);
  wk_pool_final<<<(B_ * D_) / 256, 256, 0, stream>>>(P, out);
}

// Round 2
// 74.012 us; speedup vs baseline: 1.6020x; 1.6020x over previous
//
#include <hip/hip_runtime.h>

#define B_ 8
#define S_ 512
#define D_ 768
#define LAYER0 4
#define LSTRIDE (8*512*768)   // B*S*D elements between layers
#define SCH 32                // pooling chunks per batch
#define CW (S_/SCH)           // 16 tokens per pooling chunk

// upper-triangle pair q -> (i,j), i<=j, row-major
__device__ const int QI9[45] = {0,0,0,0,0,0,0,0,0, 1,1,1,1,1,1,1,1, 2,2,2,2,2,2,2,
                                3,3,3,3,3,3, 4,4,4,4,4, 5,5,5,5, 6,6,6, 7,7, 8};
__device__ const int QJ9[45] = {0,1,2,3,4,5,6,7,8, 1,2,3,4,5,6,7,8, 2,3,4,5,6,7,8,
                                3,4,5,6,7,8, 4,5,6,7,8, 5,6,7,8, 6,7,8, 7,8, 8};

// ---------------- kernel 0: lengths per batch ----------------
__global__ void wk_len(const int* __restrict__ mask, int* __restrict__ len) {
  const int t = threadIdx.x;           // 64 threads
  const int b = t >> 3, part = t & 7;
  int acc = 0;
#pragma unroll 8
  for (int i = 0; i < 64; ++i) acc += mask[b * S_ + part * 64 + i];
  acc += __shfl_xor(acc, 1);
  acc += __shfl_xor(acc, 2);
  acc += __shfl_xor(acc, 4);
  if (part == 0) len[b] = acc - 1;
}

// ---------------- kernel 1: per-token Gram + alpha + weighted token_emb ----------------
__global__ __launch_bounds__(256) void wk_token(const float* __restrict__ hid,
                                                const int* __restrict__ len,
                                                float* __restrict__ wte,
                                                float* __restrict__ wv) {
  const int token = blockIdx.x;        // b*S + s
  const int b = token >> 9;
  const int s = token & (S_ - 1);
  const int t = threadIdx.x;

  __shared__ float pgl[256][25];       // stride 25 words (odd) -> conflict-free
  __shared__ float red[2][32][8];
  __shared__ float Gl[9][9];
  __shared__ float s_align[9], s_nov[9], s_w;

  // each thread owns d = t, t+256, t+512 for all 9 layers
  const float* base = hid + ((((size_t)LAYER0) * B_ + b) * S_ + s) * D_ + t;
  float f[9][3];
#pragma unroll
  for (int l = 0; l < 9; ++l) {
    const float* p = base + (size_t)l * LSTRIDE;
    f[l][0] = p[0];
    f[l][1] = p[256];
    f[l][2] = p[512];
  }

  // per-thread partial Gram: first 24 pairs straight to LDS, last 21 in regs
  float pg2[21];
  {
    int q = 0;
#pragma unroll
    for (int i = 0; i < 9; ++i) {
#pragma unroll
      for (int j = i; j < 9; ++j) {
        float p = f[i][0] * f[j][0] + f[i][1] * f[j][1] + f[i][2] * f[j][2];
        if (q < 24) pgl[t][q] = p;
        else pg2[q - 24] = p;
        ++q;
      }
    }
  }
  __syncthreads();

  // reduce half 0: thread (q32, sub) sums 32 rows of column q32
  {
    const int q32 = t & 31, sub = t >> 5;
    if (q32 < 24) {
      float acc = 0.f;
#pragma unroll
      for (int r = 0; r < 32; ++r) acc += pgl[sub * 32 + r][q32];
      red[0][q32][sub] = acc;
    }
  }
  __syncthreads();

  // write half 1 into pgl; concurrently finalize half-0 sums into G
#pragma unroll
  for (int q = 0; q < 21; ++q) pgl[t][q] = pg2[q];
  if (t < 24) {
    float acc = 0.f;
#pragma unroll
    for (int u = 0; u < 8; ++u) acc += red[0][t][u];
    const int i = QI9[t], j = QJ9[t];
    Gl[i][j] = acc; Gl[j][i] = acc;
  }
  __syncthreads();

  // reduce half 1
  {
    const int q32 = t & 31, sub = t >> 5;
    if (q32 < 21) {
      float acc = 0.f;
#pragma unroll
      for (int r = 0; r < 32; ++r) acc += pgl[sub * 32 + r][q32];
      red[1][q32][sub] = acc;
    }
  }
  __syncthreads();
  if (t < 21) {
    float acc = 0.f;
#pragma unroll
    for (int u = 0; u < 8; ++u) acc += red[1][t][u];
    const int i = QI9[24 + t], j = QJ9[24 + t];
    Gl[i][j] = acc; Gl[j][i] = acc;
  }
  __syncthreads();

  // lanes 0..8: per-k align/nov via Cholesky on the (<=4)x(<=4) neighbor Gram
  if (t < 9) {
    const int k = t;
    int nb[4]; int m = 0;
    if (k >= 2) { nb[m++] = k - 2; nb[m++] = k - 1; }
    if (k + 1 < 9) nb[m++] = k + 1;
    if (k + 2 < 9) nb[m++] = k + 2;
    const int n = m + 1;

    float g[4], Lc[4][4], tv[4];
    for (int i = 0; i < m; ++i) g[i] = Gl[nb[i]][k];

    for (int i = 0; i < m; ++i) {
      for (int j = 0; j <= i; ++j) {
        float sum = Gl[nb[i]][nb[j]];
        for (int p2 = 0; p2 < j; ++p2) sum -= Lc[i][p2] * Lc[j][p2];
        Lc[i][j] = (i == j) ? sqrtf(sum) : sum / Lc[j][j];
      }
    }
    float s2 = 0.f;
    for (int i = 0; i < m; ++i) {
      float sum = g[i];
      for (int p2 = 0; p2 < i; ++p2) sum -= Lc[i][p2] * tv[p2];
      tv[i] = sum / Lc[i][i];
      s2 += tv[i] * tv[i];
    }
    float ar = 0.f;
    for (int i = 0; i < m; ++i) ar += g[i] / sqrtf(Gl[nb[i]][nb[i]]);
    ar /= (float)m;

    float align = sqrtf(s2) / (ar * (2.0f * (float)n));
    float Gkk = Gl[k][k];
    float nov = sqrtf(fmaxf(Gkk - s2, 0.f)) / sqrtf(Gkk);
    s_align[k] = align;
    s_nov[k] = nov;
  }
  // lane 9: token cosine-variance -> masked weight
  if (t == 9) {
    float sc = 0.f, sc2 = 0.f;
    for (int i = 0; i < 8; ++i) {
      float nn = sqrtf(Gl[i][i]) * sqrtf(Gl[i + 1][i + 1]);
      nn = fmaxf(nn, 1e-8f);
      float ci = Gl[i][i + 1] / nn;
      sc += ci; sc2 += ci * ci;
    }
    float mean = sc * 0.125f;
    float var = (sc2 - 8.f * mean * mean) * (1.f / 7.f);
    s_w = (s < len[b]) ? var : 0.f;
  }
  __syncthreads();

  // all threads: normalize alpha, weighted token embedding for their 3 d's
  float sa = 0.f, sn = 0.f;
#pragma unroll
  for (int l = 0; l < 9; ++l) { sa += s_align[l]; sn += s_nov[l]; }
  float alpha[9]; float ss = 0.f;
#pragma unroll
  for (int l = 0; l < 9; ++l) { alpha[l] = s_align[l] / sa + s_nov[l] / sn; ss += alpha[l]; }
  const float w = s_w;
  const float inv = w / ss;            // fold mask-weight into alpha scale
  float t0 = 0.f, t1 = 0.f, t2 = 0.f;
#pragma unroll
  for (int l = 0; l < 9; ++l) {
    float a = alpha[l] * inv;
    t0 += a * f[l][0];
    t1 += a * f[l][1];
    t2 += a * f[l][2];
  }
  float* o = wte + (size_t)token * D_ + t;
  o[0] = t0; o[256] = t1; o[512] = t2;
  if (t == 0) wv[token] = w;
}

// ---------------- kernel 2: partial pooling over s-chunks (weights pre-folded) ----------------
__global__ __launch_bounds__(256) void wk_pool_partial(const float* __restrict__ wte,
                                                       const float* __restrict__ wv,
                                                       float* __restrict__ P,
                                                       float* __restrict__ Pw) {
  const int b = blockIdx.x / SCH;
  const int c = blockIdx.x % SCH;
  const int t = threadIdx.x;
  __shared__ float vl[CW];
  if (t < CW) vl[t] = wv[b * S_ + c * CW + t];
  __syncthreads();

  float a0 = 0.f, a1 = 0.f, a2 = 0.f;
  const float* base = wte + ((size_t)b * S_ + c * CW) * D_;
#pragma unroll 4
  for (int s = 0; s < CW; ++s) {
    const float* p = base + (size_t)s * D_;
    a0 += p[t];
    a1 += p[t + 256];
    a2 += p[t + 512];
  }
  float* Pp = P + (size_t)blockIdx.x * D_;
  Pp[t] = a0; Pp[t + 256] = a1; Pp[t + 512] = a2;
  if (t == 0) {
    float ws = 0.f;
#pragma unroll
    for (int s = 0; s < CW; ++s) ws += vl[s];
    Pw[blockIdx.x] = ws;
  }
}

// ---------------- kernel 3: combine partials, divide by weight sum ----------------
__global__ __launch_bounds__(256) void wk_pool_final(const float* __restrict__ P,
                                                     const float* __restrict__ Pw,
                                                     float* __restrict__ out) {
  const int i = blockIdx.x * 256 + threadIdx.x;   // 0 .. B*D-1
  const int b = i / D_;
  const int d = i % D_;
  float num = 0.f, den = 0.f;
#pragma unroll
  for (int c = 0; c < SCH; ++c) {
    num += P[((size_t)b * SCH + c) * D_ + d];
    den += Pw[b * SCH + c];
  }
  out[i] = num / den;
}

extern "C" void kernel_launch(void* const* d_in, const int* in_sizes, int n_in,
                              void* d_out, int out_size, void* d_ws, size_t ws_size,
                              hipStream_t stream) {
  const float* hid = (const float*)d_in[0];       // (13, 8, 512, 768) f32
  const int* mask = (const int*)d_in[1];          // (8, 512) i32
  float* out = (float*)d_out;                     // (8, 768) f32

  float* wte = (float*)d_ws;                      // B*S*D
  float* wv  = wte + (size_t)B_ * S_ * D_;        // B*S
  float* P   = wv + B_ * S_;                      // B*SCH*D
  float* Pw  = P + (size_t)B_ * SCH * D_;         // B*SCH
  int*   len = (int*)(Pw + B_ * SCH);             // B

  wk_len<<<1, 64, 0, stream>>>(mask, len);
  wk_token<<<B_ * S_, 256, 0, stream>>>(hid, len, wte, wv);
  wk_pool_partial<<<B_ * SCH, 256, 0, stream>>>(wte, wv, P, Pw);
  wk_pool_final<<<(B_ * D_) / 256, 256, 0, stream>>>(P, Pw, out);
}

// Round 3
// 63.131 us; speedup vs baseline: 1.8781x; 1.1724x over previous
//
#include <hip/hip_runtime.h>

#define B_ 8
#define S_ 512
#define D_ 768
#define LAYER0 4
#define LSTRIDE (8*512*768)    // B*S*D floats between layers
#define LSTRIDE4 (LSTRIDE/4)   // in float4 units
#define SCH 32                 // pooling chunks per batch
#define CW (S_/SCH)            // 16 tokens per pooling chunk

// upper-triangle pair q -> (i,j), i<=j, row-major
__device__ const int QI9[45] = {0,0,0,0,0,0,0,0,0, 1,1,1,1,1,1,1,1, 2,2,2,2,2,2,2,
                                3,3,3,3,3,3, 4,4,4,4,4, 5,5,5,5, 6,6,6, 7,7, 8};
__device__ const int QJ9[45] = {0,1,2,3,4,5,6,7,8, 1,2,3,4,5,6,7,8, 2,3,4,5,6,7,8,
                                3,4,5,6,7,8, 4,5,6,7,8, 5,6,7,8, 6,7,8, 7,8, 8};

__device__ __forceinline__ float dot4(const float4& a, const float4& b) {
  return fmaf(a.x, b.x, fmaf(a.y, b.y, fmaf(a.z, b.z, a.w * b.w)));
}

// ---------------- kernel 1: per-token Gram + alpha + token_emb + var ----------------
__global__ __launch_bounds__(192) void wk_token(const float* __restrict__ hid,
                                                float* __restrict__ wte,
                                                float* __restrict__ wv) {
  const int token = blockIdx.x;        // b*S + s
  const int b = token >> 9;
  const int s = token & (S_ - 1);
  const int t = threadIdx.x;

  __shared__ float pgl[192][25];       // stride 25 words (odd) -> conflict-free
  __shared__ float red[2][24][6];
  __shared__ float Gl[9][9];
  __shared__ float s_align[9], s_nov[9];

  // each thread owns d = 4t..4t+3 for all 9 layers (one dwordx4 per layer)
  const float4* base = (const float4*)(hid + ((((size_t)LAYER0) * B_ + b) * S_ + s) * D_) + t;
  float4 f[9];
#pragma unroll
  for (int l = 0; l < 9; ++l) f[l] = base[(size_t)l * LSTRIDE4];

  // per-thread partial Gram: first 24 pairs straight to LDS, last 21 in regs
  float pg2[21];
  {
    int q = 0;
#pragma unroll
    for (int i = 0; i < 9; ++i) {
#pragma unroll
      for (int j = i; j < 9; ++j) {
        float p = dot4(f[i], f[j]);
        if (q < 24) pgl[t][q] = p;
        else pg2[q - 24] = p;
        ++q;
      }
    }
  }
  __syncthreads();

  // reduce half 0: thread (q, sub) sums 32 rows of column q
  {
    const int q = t & 31, sub = t >> 5;   // sub in 0..5
    if (q < 24) {
      float acc = 0.f;
#pragma unroll
      for (int r = 0; r < 32; ++r) acc += pgl[sub * 32 + r][q];
      red[0][q][sub] = acc;
    }
  }
  __syncthreads();

  // write half 1 into pgl; concurrently finalize half-0 sums into G
#pragma unroll
  for (int q = 0; q < 21; ++q) pgl[t][q] = pg2[q];
  if (t < 24) {
    float acc = 0.f;
#pragma unroll
    for (int u = 0; u < 6; ++u) acc += red[0][t][u];
    const int i = QI9[t], j = QJ9[t];
    Gl[i][j] = acc; Gl[j][i] = acc;
  }
  __syncthreads();

  // reduce half 1
  {
    const int q = t & 31, sub = t >> 5;
    if (q < 21) {
      float acc = 0.f;
#pragma unroll
      for (int r = 0; r < 32; ++r) acc += pgl[sub * 32 + r][q];
      red[1][q][sub] = acc;
    }
  }
  __syncthreads();
  if (t < 21) {
    float acc = 0.f;
#pragma unroll
    for (int u = 0; u < 6; ++u) acc += red[1][t][u];
    const int i = QI9[24 + t], j = QJ9[24 + t];
    Gl[i][j] = acc; Gl[j][i] = acc;
  }
  __syncthreads();

  // lanes 0..8: per-k align/nov via Cholesky on the (<=4)x(<=4) neighbor Gram
  if (t < 9) {
    const int k = t;
    int nb[4]; int m = 0;
    if (k >= 2) { nb[m++] = k - 2; nb[m++] = k - 1; }
    if (k + 1 < 9) nb[m++] = k + 1;
    if (k + 2 < 9) nb[m++] = k + 2;
    const int n = m + 1;

    float g[4], Lc[4][4], tv[4];
    for (int i = 0; i < m; ++i) g[i] = Gl[nb[i]][k];

    for (int i = 0; i < m; ++i) {
      for (int j = 0; j <= i; ++j) {
        float sum = Gl[nb[i]][nb[j]];
        for (int p2 = 0; p2 < j; ++p2) sum -= Lc[i][p2] * Lc[j][p2];
        Lc[i][j] = (i == j) ? sqrtf(sum) : sum / Lc[j][j];
      }
    }
    float s2 = 0.f;
    for (int i = 0; i < m; ++i) {
      float sum = g[i];
      for (int p2 = 0; p2 < i; ++p2) sum -= Lc[i][p2] * tv[p2];
      tv[i] = sum / Lc[i][i];
      s2 += tv[i] * tv[i];
    }
    float ar = 0.f;
    for (int i = 0; i < m; ++i) ar += g[i] / sqrtf(Gl[nb[i]][nb[i]]);
    ar /= (float)m;

    float align = sqrtf(s2) / (ar * (2.0f * (float)n));
    float Gkk = Gl[k][k];
    float nov = sqrtf(fmaxf(Gkk - s2, 0.f)) / sqrtf(Gkk);
    s_align[k] = align;
    s_nov[k] = nov;
  }
  // lane 9: token cosine-variance (unmasked; mask applied in pooling)
  if (t == 9) {
    float sc = 0.f, sc2 = 0.f;
    for (int i = 0; i < 8; ++i) {
      float nn = sqrtf(Gl[i][i]) * sqrtf(Gl[i + 1][i + 1]);
      nn = fmaxf(nn, 1e-8f);
      float ci = Gl[i][i + 1] / nn;
      sc += ci; sc2 += ci * ci;
    }
    float mean = sc * 0.125f;
    wv[token] = (sc2 - 8.f * mean * mean) * (1.f / 7.f);
  }
  __syncthreads();

  // all threads: normalize alpha, token embedding for their 4 d's
  float sa = 0.f, sn = 0.f;
#pragma unroll
  for (int l = 0; l < 9; ++l) { sa += s_align[l]; sn += s_nov[l]; }
  float alpha[9]; float ss = 0.f;
#pragma unroll
  for (int l = 0; l < 9; ++l) { alpha[l] = s_align[l] / sa + s_nov[l] / sn; ss += alpha[l]; }
  const float inv = 1.f / ss;
  float t0 = 0.f, t1 = 0.f, t2 = 0.f, t3 = 0.f;
#pragma unroll
  for (int l = 0; l < 9; ++l) {
    float a = alpha[l] * inv;
    t0 += a * f[l].x;
    t1 += a * f[l].y;
    t2 += a * f[l].z;
    t3 += a * f[l].w;
  }
  ((float4*)(wte + (size_t)token * D_))[t] = make_float4(t0, t1, t2, t3);
}

// ---------------- kernel 2: masked weighted partial pooling over s-chunks ----------------
__global__ __launch_bounds__(192) void wk_pool_partial(const float* __restrict__ wte,
                                                       const float* __restrict__ wv,
                                                       const int* __restrict__ mask,
                                                       float* __restrict__ P,
                                                       float* __restrict__ Pw) {
  const int b = blockIdx.x / SCH;
  const int c = blockIdx.x % SCH;
  const int t = threadIdx.x;
  const int lane = t & 63, wid = t >> 6;

  __shared__ float vl[CW];
  __shared__ int redm[3];
  __shared__ int s_len;

  // mask row sum -> len (each thread <=3 ints; row is L2-hot)
  int acc = 0;
  if (t < S_) acc = mask[b * S_ + t];
  {
    int i2 = t + 192; acc += mask[b * S_ + i2];           // 192..383
    int i3 = t + 384; if (i3 < S_) acc += mask[b * S_ + i3];
  }
  acc += __shfl_xor(acc, 32); acc += __shfl_xor(acc, 16); acc += __shfl_xor(acc, 8);
  acc += __shfl_xor(acc, 4);  acc += __shfl_xor(acc, 2);  acc += __shfl_xor(acc, 1);
  if (lane == 0) redm[wid] = acc;
  if (t < CW) vl[t] = wv[b * S_ + c * CW + t];
  __syncthreads();
  if (t == 0) s_len = redm[0] + redm[1] + redm[2] - 1;
  __syncthreads();
  const int len = s_len;

  float a0 = 0.f, a1 = 0.f, a2 = 0.f, a3 = 0.f;
  const float4* base = (const float4*)(wte + ((size_t)b * S_ + c * CW) * D_) + t;
  float wsum = 0.f;
#pragma unroll 4
  for (int s = 0; s < CW; ++s) {
    float w = (c * CW + s < len) ? vl[s] : 0.f;
    wsum += w;
    float4 p = base[s * (D_ / 4)];
    a0 += w * p.x; a1 += w * p.y; a2 += w * p.z; a3 += w * p.w;
  }
  ((float4*)(P + (size_t)blockIdx.x * D_))[t] = make_float4(a0, a1, a2, a3);
  if (t == 0) Pw[blockIdx.x] = wsum;
}

// ---------------- kernel 3: combine partials, divide by weight sum ----------------
__global__ __launch_bounds__(256) void wk_pool_final(const float* __restrict__ P,
                                                     const float* __restrict__ Pw,
                                                     float* __restrict__ out) {
  const int i = blockIdx.x * 256 + threadIdx.x;   // 0 .. B*(D/4)-1 = 1535
  const int b = i / (D_ / 4);
  const int d4 = i % (D_ / 4);
  float n0 = 0.f, n1 = 0.f, n2 = 0.f, n3 = 0.f, den = 0.f;
#pragma unroll
  for (int c = 0; c < SCH; ++c) {
    float4 p = ((const float4*)P)[((size_t)b * SCH + c) * (D_ / 4) + d4];
    n0 += p.x; n1 += p.y; n2 += p.z; n3 += p.w;
    den += Pw[b * SCH + c];
  }
  float inv = 1.f / den;
  ((float4*)out)[i] = make_float4(n0 * inv, n1 * inv, n2 * inv, n3 * inv);
}

extern "C" void kernel_launch(void* const* d_in, const int* in_sizes, int n_in,
                              void* d_out, int out_size, void* d_ws, size_t ws_size,
                              hipStream_t stream) {
  const float* hid = (const float*)d_in[0];       // (13, 8, 512, 768) f32
  const int* mask = (const int*)d_in[1];          // (8, 512) i32
  float* out = (float*)d_out;                     // (8, 768) f32

  float* wte = (float*)d_ws;                      // B*S*D
  float* wv  = wte + (size_t)B_ * S_ * D_;        // B*S
  float* P   = wv + B_ * S_;                      // B*SCH*D
  float* Pw  = P + (size_t)B_ * SCH * D_;         // B*SCH

  wk_token<<<B_ * S_, 192, 0, stream>>>(hid, wte, wv);
  wk_pool_partial<<<B_ * SCH, 192, 0, stream>>>(wte, wv, mask, P, Pw);
  wk_pool_final<<<(B_ * (D_ / 4) + 255) / 256, 256, 0, stream>>>(P, Pw, out);
}

// Round 5
// 52.322 us; speedup vs baseline: 2.2661x; 1.2066x over previous
//
#include <hip/hip_runtime.h>

#define B_ 8
#define S_ 512
#define D_ 768
#define LAYER0 4
#define LSTRIDE4 (8*512*768/4)   // float4 between layers
#define SCH 32                   // pooling chunks per batch
#define CW (S_/SCH)              // 16 tokens per chunk

// upper-triangle pair q -> (i,j), i<=j, row-major
__device__ const int QI9[45] = {0,0,0,0,0,0,0,0,0, 1,1,1,1,1,1,1,1, 2,2,2,2,2,2,2,
                                3,3,3,3,3,3, 4,4,4,4,4, 5,5,5,5, 6,6,6, 7,7, 8};
__device__ const int QJ9[45] = {0,1,2,3,4,5,6,7,8, 1,2,3,4,5,6,7,8, 2,3,4,5,6,7,8,
                                3,4,5,6,7,8, 4,5,6,7,8, 5,6,7,8, 6,7,8, 7,8, 8};

__device__ __forceinline__ float dot4(const float4& a, const float4& b) {
  return fmaf(a.x, b.x, fmaf(a.y, b.y, fmaf(a.z, b.z, a.w * b.w)));
}

// ---------------- kernel 1: per-token Gram (f32) + alpha + weighted te, 1 wave/token ----------------
__global__ __launch_bounds__(64) void wk_token(const float* __restrict__ hid,
                                               const int* __restrict__ mask,
                                               float* __restrict__ wte,
                                               float* __restrict__ wv) {
  const int token = blockIdx.x;        // b*S + s
  const int b = token >> 9;
  const int s = token & (S_ - 1);
  const int t = threadIdx.x;           // 0..63, one wave

  __shared__ float pgl[64][46];        // [lane][pair], stride 46 (2-way max aliasing ~ free)
  __shared__ float Gsym[81];

  // mask length for this batch (2 KB row, L2-hot)
  int mlen;
  {
    const int4* mp = (const int4*)(mask + b * S_);
    int4 m1 = mp[t];
    int4 m2 = mp[t + 64];
    int acc = m1.x + m1.y + m1.z + m1.w + m2.x + m2.y + m2.z + m2.w;
    acc += __shfl_xor(acc, 32); acc += __shfl_xor(acc, 16);
    acc += __shfl_xor(acc, 8);  acc += __shfl_xor(acc, 4);
    acc += __shfl_xor(acc, 2);  acc += __shfl_xor(acc, 1);
    mlen = acc - 1;
  }

  // each lane owns 12 dims: float4 indices t, t+64, t+128 (3 coalesced dwordx4 per layer)
  const float4* base = (const float4*)hid
      + (((size_t)LAYER0 * B_ + b) * S_ + s) * (D_ / 4) + t;
  float4 f[27];
#pragma unroll
  for (int l = 0; l < 9; ++l) {
#pragma unroll
    for (int c = 0; c < 3; ++c) f[l * 3 + c] = base[(size_t)l * LSTRIDE4 + c * 64];
  }

  // 45 pair partial dots -> LDS
  {
    int q = 0;
#pragma unroll
    for (int i = 0; i < 9; ++i) {
#pragma unroll
      for (int j = i; j < 9; ++j) {
        float d = dot4(f[i * 3], f[j * 3])
                + dot4(f[i * 3 + 1], f[j * 3 + 1])
                + dot4(f[i * 3 + 2], f[j * 3 + 2]);
        pgl[t][q] = d;
        ++q;
      }
    }
  }
  __syncthreads();

  // column sums: lane q (<45) owns pair q
  if (t < 45) {
    float tot = 0.f;
#pragma unroll
    for (int r = 0; r < 64; r += 2) tot += pgl[r][t] + pgl[r + 1][t];
    Gsym[QI9[t] * 9 + QJ9[t]] = tot;
    Gsym[QJ9[t] * 9 + QI9[t]] = tot;
  }
  __syncthreads();

  // lanes 0..8: per-k align/nov via Cholesky; lane 9: cosine variance
  float align = 0.f, nov = 0.f, var = 0.f;
  if (t < 9) {
    const int k = t;
    int nb[4]; int m = 0;
    if (k >= 2) { nb[m++] = k - 2; nb[m++] = k - 1; }
    if (k + 1 < 9) nb[m++] = k + 1;
    if (k + 2 < 9) nb[m++] = k + 2;
    const int n = m + 1;

    float g[4], Lc[4][4], tv[4];
    for (int i = 0; i < m; ++i) g[i] = Gsym[nb[i] * 9 + k];

    for (int i = 0; i < m; ++i) {
      for (int j = 0; j <= i; ++j) {
        float sum = Gsym[nb[i] * 9 + nb[j]];
        for (int p = 0; p < j; ++p) sum -= Lc[i][p] * Lc[j][p];
        Lc[i][j] = (i == j) ? sqrtf(sum) : sum / Lc[j][j];
      }
    }
    float s2 = 0.f;
    for (int i = 0; i < m; ++i) {
      float sum = g[i];
      for (int p = 0; p < i; ++p) sum -= Lc[i][p] * tv[p];
      tv[i] = sum / Lc[i][i];
      s2 += tv[i] * tv[i];
    }
    float ar = 0.f;
    for (int i = 0; i < m; ++i) ar += g[i] / sqrtf(Gsym[nb[i] * 9 + nb[i]]);
    ar /= (float)m;

    align = sqrtf(s2) / (ar * (2.0f * (float)n));
    float Gkk = Gsym[k * 9 + k];
    nov = sqrtf(fmaxf(Gkk - s2, 0.f)) / sqrtf(Gkk);
  }
  if (t == 9) {
    float sc = 0.f, sc2 = 0.f;
    for (int i = 0; i < 8; ++i) {
      float nn = sqrtf(Gsym[i * 9 + i]) * sqrtf(Gsym[(i + 1) * 9 + i + 1]);
      nn = fmaxf(nn, 1e-8f);
      float ci = Gsym[i * 9 + i + 1] / nn;
      sc += ci; sc2 += ci * ci;
    }
    float mean = sc * 0.125f;
    var = (sc2 - 8.f * mean * mean) * (1.f / 7.f);
  }

  float w = __shfl(var, 9);
  if (s >= mlen) w = 0.f;              // mask fold

  float sa = 0.f, sn = 0.f;
#pragma unroll
  for (int i = 0; i < 9; ++i) { sa += __shfl(align, i); sn += __shfl(nov, i); }
  float alpha = align / sa + nov / sn; // 0 on lanes >= 9
  float ss = 0.f;
#pragma unroll
  for (int i = 0; i < 9; ++i) ss += __shfl(alpha, i);

  // broadcast normalized, mask-weighted alphas; write w * token_emb
  const float inv = w / ss;
  float a9[9];
#pragma unroll
  for (int l = 0; l < 9; ++l) a9[l] = __shfl(alpha, l) * inv;

  float4* o = (float4*)wte + (size_t)token * (D_ / 4) + t;
#pragma unroll
  for (int c = 0; c < 3; ++c) {
    float4 acc = make_float4(0.f, 0.f, 0.f, 0.f);
#pragma unroll
    for (int l = 0; l < 9; ++l) {
      float a = a9[l];
      float4 p = f[l * 3 + c];
      acc.x += a * p.x; acc.y += a * p.y; acc.z += a * p.z; acc.w += a * p.w;
    }
    o[c * 64] = acc;
  }
  if (t == 0) wv[token] = w;
}

// ---------------- kernel 2: plain partial sums over 16-token chunks ----------------
__global__ __launch_bounds__(192) void wk_pool(const float* __restrict__ wte,
                                               const float* __restrict__ wv,
                                               float* __restrict__ P,
                                               float* __restrict__ Pw) {
  const int b = blockIdx.x >> 5;
  const int c = blockIdx.x & 31;
  const int t = threadIdx.x;

  float4 a = make_float4(0.f, 0.f, 0.f, 0.f);
  const float4* base = (const float4*)wte + ((size_t)b * S_ + c * CW) * (D_ / 4) + t;
#pragma unroll 4
  for (int sl = 0; sl < CW; ++sl) {
    float4 p = base[sl * (D_ / 4)];
    a.x += p.x; a.y += p.y; a.z += p.z; a.w += p.w;
  }
  ((float4*)P)[(size_t)blockIdx.x * (D_ / 4) + t] = a;
  if (t == 0) {
    float ws = 0.f;
#pragma unroll
    for (int i = 0; i < CW; ++i) ws += wv[b * S_ + c * CW + i];
    Pw[blockIdx.x] = ws;
  }
}

// ---------------- kernel 3: combine partials, divide by weight sum ----------------
__global__ __launch_bounds__(256) void wk_pool_final(const float* __restrict__ P,
                                                     const float* __restrict__ Pw,
                                                     float* __restrict__ out) {
  const int i = blockIdx.x * 256 + threadIdx.x;   // 0 .. B*(D/4)-1 = 1535
  const int b = i / (D_ / 4);
  const int d4 = i % (D_ / 4);
  float n0 = 0.f, n1 = 0.f, n2 = 0.f, n3 = 0.f, den = 0.f;
#pragma unroll
  for (int c = 0; c < SCH; ++c) {
    float4 p = ((const float4*)P)[((size_t)b * SCH + c) * (D_ / 4) + d4];
    n0 += p.x; n1 += p.y; n2 += p.z; n3 += p.w;
    den += Pw[b * SCH + c];
  }
  float inv = 1.f / den;
  ((float4*)out)[i] = make_float4(n0 * inv, n1 * inv, n2 * inv, n3 * inv);
}

extern "C" void kernel_launch(void* const* d_in, const int* in_sizes, int n_in,
                              void* d_out, int out_size, void* d_ws, size_t ws_size,
                              hipStream_t stream) {
  const float* hid = (const float*)d_in[0];       // (13, 8, 512, 768) f32
  const int* mask = (const int*)d_in[1];          // (8, 512) i32
  float* out = (float*)d_out;                     // (8, 768) f32

  float* wte = (float*)d_ws;                      // B*S*D  (w * token_emb)
  float* wv  = wte + (size_t)B_ * S_ * D_;        // B*S    (token weights)
  float* P   = wv + B_ * S_;                      // B*SCH*D
  float* Pw  = P + (size_t)B_ * SCH * D_;         // B*SCH

  wk_token<<<B_ * S_, 64, 0, stream>>>(hid, mask, wte, wv);
  wk_pool<<<B_ * SCH, 192, 0, stream>>>(wte, wv, P, Pw);
  wk_pool_final<<<(B_ * (D_ / 4) + 255) / 256, 256, 0, stream>>>(P, Pw, out);
}

// Round 6
// 52.286 us; speedup vs baseline: 2.2676x; 1.0007x over previous
//
#include <hip/hip_runtime.h>

#define B_ 8
#define S_ 512
#define D_ 768
#define LAYER0 4
#define LSTRIDE4 (8*512*768/4)   // float4 between layers
#define SCH 32                   // pooling chunks per batch
#define CW (S_/SCH)              // 16 tokens per chunk

// upper-triangle pair q -> (i,j), i<=j, row-major
__device__ const int QI9[45] = {0,0,0,0,0,0,0,0,0, 1,1,1,1,1,1,1,1, 2,2,2,2,2,2,2,
                                3,3,3,3,3,3, 4,4,4,4,4, 5,5,5,5, 6,6,6, 7,7, 8};
__device__ const int QJ9[45] = {0,1,2,3,4,5,6,7,8, 1,2,3,4,5,6,7,8, 2,3,4,5,6,7,8,
                                3,4,5,6,7,8, 4,5,6,7,8, 5,6,7,8, 6,7,8, 7,8, 8};

__device__ __forceinline__ float dot4(const float4& a, const float4& b) {
  return fmaf(a.x, b.x, fmaf(a.y, b.y, fmaf(a.z, b.z, a.w * b.w)));
}

// ---------------- kernel 1: per-token Gram (f32) + alpha + weighted te, 1 wave/token ----------------
__global__ __launch_bounds__(64) void wk_token(const float* __restrict__ hid,
                                               const int* __restrict__ mask,
                                               float* __restrict__ wte,
                                               float* __restrict__ wv) {
  const int token = blockIdx.x;        // b*S + s
  const int b = token >> 9;
  const int s = token & (S_ - 1);
  const int t = threadIdx.x;           // 0..63, one wave

  __shared__ float pgl[64][45];        // stride 45: gcd(45%32,32)=1 -> 2-way max (free)
  __shared__ float Gsym[81];
  __shared__ float st[19];             // align[0..8], nov[9..17], var[18]

  // mask is monotone (arange < length): s < len=length-1  <=>  mask[s+1]==1.
  // b,s are block-uniform -> scalar load.
  const int valid = (s < S_ - 1) ? mask[b * S_ + s + 1] : 0;

  // each lane owns 12 dims: float4 indices t, t+64, t+128 (3 coalesced dwordx4 per layer)
  const float4* base = (const float4*)hid
      + (((size_t)LAYER0 * B_ + b) * S_ + s) * (D_ / 4) + t;
  float4 f[27];
#pragma unroll
  for (int l = 0; l < 9; ++l) {
#pragma unroll
    for (int c = 0; c < 3; ++c) f[l * 3 + c] = base[(size_t)l * LSTRIDE4 + c * 64];
  }

  // 45 pair partial dots -> LDS (contiguous q -> vectorizable ds_writes)
  {
    int q = 0;
#pragma unroll
    for (int i = 0; i < 9; ++i) {
#pragma unroll
      for (int j = i; j < 9; ++j) {
        pgl[t][q] = dot4(f[i * 3], f[j * 3])
                  + dot4(f[i * 3 + 1], f[j * 3 + 1])
                  + dot4(f[i * 3 + 2], f[j * 3 + 2]);
        ++q;
      }
    }
  }
  __syncthreads();

  // column sums: lane q (<45) owns pair q; 4 accumulators break the FP chain
  if (t < 45) {
    float a0 = 0.f, a1 = 0.f, a2 = 0.f, a3 = 0.f;
#pragma unroll
    for (int r = 0; r < 64; r += 4) {
      a0 += pgl[r][t]; a1 += pgl[r + 1][t]; a2 += pgl[r + 2][t]; a3 += pgl[r + 3][t];
    }
    float tot = (a0 + a1) + (a2 + a3);
    Gsym[QI9[t] * 9 + QJ9[t]] = tot;
    Gsym[QJ9[t] * 9 + QI9[t]] = tot;
  }
  __syncthreads();

  // lanes 0..8: per-k align/nov via Cholesky; lane 9: cosine variance -> LDS
  if (t < 9) {
    const int k = t;
    int nb[4]; int m = 0;
    if (k >= 2) { nb[m++] = k - 2; nb[m++] = k - 1; }
    if (k + 1 < 9) nb[m++] = k + 1;
    if (k + 2 < 9) nb[m++] = k + 2;
    const int n = m + 1;

    float g[4], Lc[4][4], tv[4];
    for (int i = 0; i < m; ++i) g[i] = Gsym[nb[i] * 9 + k];

    for (int i = 0; i < m; ++i) {
      for (int j = 0; j <= i; ++j) {
        float sum = Gsym[nb[i] * 9 + nb[j]];
        for (int p = 0; p < j; ++p) sum -= Lc[i][p] * Lc[j][p];
        Lc[i][j] = (i == j) ? sqrtf(sum) : sum / Lc[j][j];
      }
    }
    float s2 = 0.f;
    for (int i = 0; i < m; ++i) {
      float sum = g[i];
      for (int p = 0; p < i; ++p) sum -= Lc[i][p] * tv[p];
      tv[i] = sum / Lc[i][i];
      s2 += tv[i] * tv[i];
    }
    float ar = 0.f;
    for (int i = 0; i < m; ++i) ar += g[i] / sqrtf(Gsym[nb[i] * 9 + nb[i]]);
    ar /= (float)m;

    st[k] = sqrtf(s2) / (ar * (2.0f * (float)n));          // align
    float Gkk = Gsym[k * 9 + k];
    st[9 + k] = sqrtf(fmaxf(Gkk - s2, 0.f)) / sqrtf(Gkk);  // nov
  }
  if (t == 9) {
    float sc = 0.f, sc2 = 0.f;
    for (int i = 0; i < 8; ++i) {
      float nn = sqrtf(Gsym[i * 9 + i]) * sqrtf(Gsym[(i + 1) * 9 + i + 1]);
      nn = fmaxf(nn, 1e-8f);
      float ci = Gsym[i * 9 + i + 1] / nn;
      sc += ci; sc2 += ci * ci;
    }
    float mean = sc * 0.125f;
    st[18] = (sc2 - 8.f * mean * mean) * (1.f / 7.f);
  }
  __syncthreads();

  // all lanes: redundant scalar epilogue from broadcast LDS reads (no shfl chains)
  const float w = valid ? st[18] : 0.f;
  float sa = 0.f, sn = 0.f;
#pragma unroll
  for (int l = 0; l < 9; ++l) { sa += st[l]; sn += st[9 + l]; }
  const float rsa = 1.f / sa, rsn = 1.f / sn;
  float a9[9]; float ss = 0.f;
#pragma unroll
  for (int l = 0; l < 9; ++l) { a9[l] = st[l] * rsa + st[9 + l] * rsn; ss += a9[l]; }
  const float inv = w / ss;

  float4* o = (float4*)wte + (size_t)token * (D_ / 4) + t;
#pragma unroll
  for (int c = 0; c < 3; ++c) {
    float4 acc = make_float4(0.f, 0.f, 0.f, 0.f);
#pragma unroll
    for (int l = 0; l < 9; ++l) {
      float a = a9[l] * inv;
      float4 p = f[l * 3 + c];
      acc.x += a * p.x; acc.y += a * p.y; acc.z += a * p.z; acc.w += a * p.w;
    }
    o[c * 64] = acc;
  }
  if (t == 0) wv[token] = w;
}

// ---------------- kernel 2: plain partial sums over 16-token chunks ----------------
__global__ __launch_bounds__(192) void wk_pool(const float* __restrict__ wte,
                                               const float* __restrict__ wv,
                                               float* __restrict__ P,
                                               float* __restrict__ Pw) {
  const int b = blockIdx.x >> 5;
  const int c = blockIdx.x & 31;
  const int t = threadIdx.x;

  float4 a = make_float4(0.f, 0.f, 0.f, 0.f);
  const float4* base = (const float4*)wte + ((size_t)b * S_ + c * CW) * (D_ / 4) + t;
#pragma unroll 4
  for (int sl = 0; sl < CW; ++sl) {
    float4 p = base[sl * (D_ / 4)];
    a.x += p.x; a.y += p.y; a.z += p.z; a.w += p.w;
  }
  ((float4*)P)[(size_t)blockIdx.x * (D_ / 4) + t] = a;
  if (t == 0) {
    float ws = 0.f;
#pragma unroll
    for (int i = 0; i < CW; ++i) ws += wv[b * S_ + c * CW + i];
    Pw[blockIdx.x] = ws;
  }
}

// ---------------- kernel 3: combine partials, divide by weight sum ----------------
__global__ __launch_bounds__(256) void wk_pool_final(const float* __restrict__ P,
                                                     const float* __restrict__ Pw,
                                                     float* __restrict__ out) {
  const int i = blockIdx.x * 256 + threadIdx.x;   // 0 .. B*(D/4)-1 = 1535
  const int b = i / (D_ / 4);
  const int d4 = i % (D_ / 4);
  float n0 = 0.f, n1 = 0.f, n2 = 0.f, n3 = 0.f, den = 0.f;
#pragma unroll
  for (int c = 0; c < SCH; ++c) {
    float4 p = ((const float4*)P)[((size_t)b * SCH + c) * (D_ / 4) + d4];
    n0 += p.x; n1 += p.y; n2 += p.z; n3 += p.w;
    den += Pw[b * SCH + c];
  }
  float inv = 1.f / den;
  ((float4*)out)[i] = make_float4(n0 * inv, n1 * inv, n2 * inv, n3 * inv);
}

extern "C" void kernel_launch(void* const* d_in, const int* in_sizes, int n_in,
                              void* d_out, int out_size, void* d_ws, size_t ws_size,
                              hipStream_t stream) {
  const float* hid = (const float*)d_in[0];       // (13, 8, 512, 768) f32
  const int* mask = (const int*)d_in[1];          // (8, 512) i32
  float* out = (float*)d_out;                     // (8, 768) f32

  float* wte = (float*)d_ws;                      // B*S*D  (w * token_emb)
  float* wv  = wte + (size_t)B_ * S_ * D_;        // B*S    (token weights)
  float* P   = wv + B_ * S_;                      // B*SCH*D
  float* Pw  = P + (size_t)B_ * SCH * D_;         // B*SCH

  wk_token<<<B_ * S_, 64, 0, stream>>>(hid, mask, wte, wv);
  wk_pool<<<B_ * SCH, 192, 0, stream>>>(wte, wv, P, Pw);
  wk_pool_final<<<(B_ * (D_ / 4) + 255) / 256, 256, 0, stream>>>(P, Pw, out);
}